// Round 14
// baseline (431.560 us; speedup 1.0000x reference)
//
#include <hip/hip_runtime.h>
#include <stdint.h>

#define WW 1024
#define HH 1024
#define NB 4
#define HW (HH * WW)
#define NPIX (NB * HW)        // 4194304
#define NT 4096               // 32x32 tiles per input
#define INVALID 0xFFFFFFFFu
#define RS 8                  // rows per open strip

// counter layout (uint32 words):
//   bank b misc at b*16: [0]=min_bits [1]=max_bits [2]=root0 flag
//   fg/comp u64 slots:  word FCW(b,s) = 32  + (b*8+s)*16   (8 slots/input, 64B apart)
//   link u32 slots:     word LKW(b,s) = 288 + (b*8+s)*16
#define FCW(b,s) (32 + ((b)*8+(s))*16)
#define LKW(b,s) (288 + ((b)*8+(s))*16)
#define CNT_WORDS 544
#define FLAG_WORDS (2 * 4 * NT)   // 2 banks x 4 families x 4096 tiles

__global__ void k_zero(uint32_t* c) {
    int stride = gridDim.x * blockDim.x;
    for (int i = blockIdx.x * blockDim.x + threadIdx.x;
         i < CNT_WORDS + FLAG_WORDS; i += stride)
        c[i] = (i == 0 || i == 16) ? 0x7F800000u : 0u;
}

// ---- open strip: cross erode+dilate + per-input min/max (r11-identical) ----
__device__ __forceinline__ void do_open_strip(const float* __restrict__ in,
                                              float* __restrict__ out,
                                              uint32_t* c, int strip, uint32_t* S) {
    int b  = strip >> 7;
    int y0 = (strip & 127) * RS;
    int t  = threadIdx.x;
    float* sx = (float*)S;
    float* sw = (float*)S + 2580;
    float* smin = (float*)S + 5160;
    float* smax = (float*)S + 5164;
    const float4* inb = (const float4*)(in + (size_t)b * HW);
    float4* outb      = (float4*)(out + (size_t)b * HW);

    float4 A[RS + 4];
    #pragma unroll
    for (int j = 0; j < RS + 4; j++) {
        int iy = y0 - 2 + j;
        if (iy >= 0 && iy < HH) A[j] = inb[iy * 256 + t];
        else A[j] = make_float4(1e10f, 1e10f, 1e10f, 1e10f);  // erosion pad
    }
    #pragma unroll
    for (int rr = 0; rr < RS + 2; rr++) { sx[rr * 258 + t + 1] = A[rr + 1].x; sw[rr * 258 + t + 1] = A[rr + 1].w; }
    if (t < RS + 2) { sw[t * 258 + 0] = 1e10f; sx[t * 258 + 257] = 1e10f; }
    __syncthreads();

    float4 E[RS + 2];
    #pragma unroll
    for (int rr = 0; rr < RS + 2; rr++) {
        int ey = y0 - 1 + rr;
        float lw = sw[rr * 258 + t], rw = sx[rr * 258 + t + 2];
        float4 v = A[rr + 1];
        float hx = fminf(fminf(lw, v.x), v.y);
        float hy = fminf(fminf(v.x, v.y), v.z);
        float hz = fminf(fminf(v.y, v.z), v.w);
        float hw = fminf(fminf(v.z, v.w), rw);
        float4 e;
        e.x = fminf(hx, fminf(A[rr].x, A[rr + 2].x));
        e.y = fminf(hy, fminf(A[rr].y, A[rr + 2].y));
        e.z = fminf(hz, fminf(A[rr].z, A[rr + 2].z));
        e.w = fminf(hw, fminf(A[rr].w, A[rr + 2].w));
        if (ey < 0 || ey >= HH) e = make_float4(-1e10f, -1e10f, -1e10f, -1e10f);
        E[rr] = e;
    }
    __syncthreads();

    #pragma unroll
    for (int d = 0; d < RS; d++) { sx[d * 258 + t + 1] = E[d + 1].x; sw[d * 258 + t + 1] = E[d + 1].w; }
    if (t < RS) { sw[t * 258 + 0] = -1e10f; sx[t * 258 + 257] = -1e10f; }
    __syncthreads();

    float lmin = __uint_as_float(0x7F800000u);
    float lmax = 0.0f;
    #pragma unroll
    for (int d = 0; d < RS; d++) {
        float lw = sw[d * 258 + t], rw = sx[d * 258 + t + 2];
        float4 v = E[d + 1];
        float hx = fmaxf(fmaxf(lw, v.x), v.y);
        float hy = fmaxf(fmaxf(v.x, v.y), v.z);
        float hz = fmaxf(fmaxf(v.y, v.z), v.w);
        float hw = fmaxf(fmaxf(v.z, v.w), rw);
        float4 o;
        o.x = fmaxf(hx, fmaxf(E[d].x, E[d + 2].x));
        o.y = fmaxf(hy, fmaxf(E[d].y, E[d + 2].y));
        o.z = fmaxf(hz, fmaxf(E[d].z, E[d + 2].z));
        o.w = fmaxf(hw, fmaxf(E[d].w, E[d + 2].w));
        outb[(y0 + d) * 256 + t] = o;
        lmin = fminf(lmin, fminf(fminf(o.x, o.y), fminf(o.z, o.w)));
        lmax = fmaxf(lmax, fmaxf(fmaxf(o.x, o.y), fmaxf(o.z, o.w)));
    }
    for (int off = 32; off > 0; off >>= 1) {
        lmin = fminf(lmin, __shfl_down(lmin, off));
        lmax = fmaxf(lmax, __shfl_down(lmax, off));
    }
    if ((t & 63) == 0) { smin[t >> 6] = lmin; smax[t >> 6] = lmax; }
    __syncthreads();
    if (t == 0) {
        float m0 = fminf(fminf(smin[0], smin[1]), fminf(smin[2], smin[3]));
        float m1 = fmaxf(fmaxf(smax[0], smax[1]), fmaxf(smax[2], smax[3]));
        atomicMin(&c[0], __float_as_uint(m0));  // non-negative floats: bit order == float order
        atomicMax(&c[1], __float_as_uint(m1));
    }
}

// exact binarize threshold: smallest float B with (B-mn)/denom >= 0.5;
// v >= B is then bitwise identical to the reference predicate for every v.
__device__ __forceinline__ float calc_thr(const uint32_t* c, int bank) {
    float mn = __uint_as_float(c[bank * 16 + 0]);
    float mx = __uint_as_float(c[bank * 16 + 1]);
    float denom = (mx - mn) + 1e-10f;   // reference association order
    uint32_t lo = 0, hi = 0x7F800000u;
    while (lo < hi) {
        uint32_t mid = (lo + hi) >> 1;
        float q = (__uint_as_float(mid) - mn) / denom;  // IEEE f32 div
        if (q >= 0.5f) hi = mid; else lo = mid + 1;
    }
    return __uint_as_float(lo);
}

// ---------------- LDS union-find (wave-private region) ----------------------
__device__ __forceinline__ uint32_t lload(uint32_t* lp, uint32_t x) {
    return __hip_atomic_load(&lp[x], __ATOMIC_RELAXED, __HIP_MEMORY_SCOPE_WORKGROUP);
}
__device__ __forceinline__ uint32_t lfind(uint32_t* lp, uint32_t x) {
    uint32_t p = lload(lp, x);
    while (p != x) {
        uint32_t gp = lload(lp, p);
        if (gp != p)
            __hip_atomic_store(&lp[x], gp, __ATOMIC_RELAXED, __HIP_MEMORY_SCOPE_WORKGROUP);
        x = p; p = gp;
    }
    return x;
}
__device__ uint32_t lunion(uint32_t* lp, uint32_t a, uint32_t b) {
    uint32_t ra = lfind(lp, a), rb = lfind(lp, b);
    while (ra != rb) {
        uint32_t hi = ra > rb ? ra : rb;
        uint32_t lo = ra ^ rb ^ hi;
        uint32_t old = atomicCAS(&lp[lo], lo, hi);
        if (old == lo) return 1;  // killed exactly one root
        ra = lfind(lp, old);
        rb = lfind(lp, hi);
    }
    return 0;
}
__device__ __forceinline__ int run_len(uint32_t bits) {  // consecutive 1s from bit 0
    return (int)__builtin_ctzll(~(uint64_t)bits);
}

// ---- binarize + tile-local run CCL + compact border-node emit (r9) ---------
__device__ void do_ccl_tile(const float* __restrict__ opened, uint8_t* __restrict__ desc,
                            uint32_t* __restrict__ parent, uint32_t* cbase, int bank,
                            int tile, int L, uint32_t* M, uint32_t* LP, uint32_t* SM,
                            float thr) {
    int b  = tile >> 10;
    int tt = tile & 1023;
    int ty0 = (tt >> 5) << 5;
    int tx0 = (tt & 31) << 5;
    uint32_t base = (uint32_t)b * HW + (uint32_t)ty0 * WW + tx0;

    #pragma unroll
    for (int q = 0; q < 4; q++) {
        uint32_t u = (uint32_t)L + 64u * q;
        ((uint4*)LP)[u] = make_uint4(4*u, 4*u+1, 4*u+2, 4*u+3);
        ((uint4*)SM)[u] = make_uint4(INVALID, INVALID, INVALID, INVALID);
    }

    // dense loads: lane L covers row (L>>3)+8q, cols (L&7)*4..+3
    int r8 = L >> 3, c8 = (L & 7) << 2;
    uint32_t fgcnt = 0;
    #pragma unroll
    for (int q = 0; q < 4; q++) {
        int rr = r8 + 8 * q;
        float4 v = *(const float4*)(opened + base + (uint32_t)rr * WW + c8);
        uint32_t pb = (v.x >= thr ? 1u : 0u) | (v.y >= thr ? 2u : 0u)
                    | (v.z >= thr ? 4u : 0u) | (v.w >= thr ? 8u : 0u);
        fgcnt += __popc(pb);
        uint32_t part = pb << c8;
        part |= __shfl_xor(part, 1, 8);
        part |= __shfl_xor(part, 2, 8);
        part |= __shfl_xor(part, 4, 8);
        if ((L & 7) == 0) M[rr] = part;
    }
    __syncthreads();

    // unions: lane owns half-row (r = L>>1, half h = L&1)
    int r = L >> 1, h = L & 1;
    uint32_t rowm = M[r];
    uint32_t halfsel = 0xFFFFu << (16 * h);
    uint32_t starts = (rowm & ~(rowm << 1)) & halfsel;
    uint32_t runs = __popc(starts);
    uint32_t links = 0;
    if (r > 0 && starts) {
        uint32_t up = M[r - 1];
        uint32_t w0 = starts;
        while (w0) {
            int lx = __builtin_ctz(w0); w0 &= w0 - 1;
            int e = lx + run_len(rowm >> lx) - 1;
            int lo = lx ? lx - 1 : 0;
            int hi = (e >= 31) ? 31 : e + 1;
            uint32_t hm = (hi == 31) ? 0xFFFFFFFFu : ((1u << (hi + 1)) - 1u);
            uint32_t w = up & hm & ~((1u << lo) - 1u);
            uint32_t repA = ((uint32_t)r << 5) + e;
            while (w) {
                int xs = __builtin_ctz(w);
                int xe = xs + run_len(up >> xs) - 1;
                links += lunion(LP, repA, (((uint32_t)r - 1) << 5) + (uint32_t)xe);
                w = (xe >= 31) ? 0u : (w & ~((1u << (xe + 1)) - 1u));
            }
        }
    }
    __syncthreads();

    // pixel-0 / label-0: isolated fg singleton at pixel 0 (all nbrs intra-tile)
    if (tile == 0 && L == 0) {
        if ((rowm & 1u) && !(rowm & 2u) && LP[0] == 0u) atomicOr(&cbase[bank * 16 + 2], 1u);
    }

    // border slot assignment: lane handles positions 2L, 2L+1; lfind from the
    // pixel's RUN REP (run end) — non-rep pixels are never linked in LP.
    uint32_t rk[2]; bool fgk[2];
    #pragma unroll
    for (int j = 0; j < 2; j++) {
        int k = 2 * L + j;
        int li = (k < 32) ? k
               : (k < 64) ? (31 * 32 + (k - 32))
               : (k < 96) ? ((k - 64) << 5)
                          : (((k - 96) << 5) + 31);
        int ly = li >> 5, lx = li & 31;
        uint32_t rm = M[ly];
        bool f = (rm >> lx) & 1u;
        fgk[j] = f;
        if (f) {
            int e = lx + run_len(rm >> lx) - 1;
            rk[j] = lfind(LP, ((uint32_t)ly << 5) + (uint32_t)e);
            atomicMin(&SM[rk[j]], (uint32_t)k);
        }
    }
    __syncthreads();

    uint32_t nodebase = (uint32_t)tile << 7;
    uint32_t d2 = 0;
    #pragma unroll
    for (int j = 0; j < 2; j++) {
        int k = 2 * L + j;
        uint32_t sb = 0xFFu;
        if (fgk[j]) {
            uint32_t s = SM[rk[j]];
            sb = s;
            if (s == (uint32_t)k) parent[nodebase + k] = nodebase + k;  // canonical only
        }
        d2 |= sb << (8 * j);
    }
    ((uint16_t*)desc)[((uint32_t)tile << 6) + L] = (uint16_t)d2;

    uint32_t pk = (fgcnt << 20) | (runs << 10) | links;
    for (int off = 32; off > 0; off >>= 1) pk += __shfl_down(pk, off);
    if (L == 0) {
        uint32_t fgs = pk >> 20, rns = (pk >> 10) & 1023u, lks = pk & 1023u;
        unsigned long long v = ((unsigned long long)(rns - lks) << 32) | fgs;
        if (v) atomicAdd((unsigned long long*)&cbase[FCW(bank, tile & 7)], v);
    }
    __syncthreads();
}

// ---------------- global union-find on compact nodes (device scope) ---------
__device__ __forceinline__ uint32_t pload(uint32_t* P, uint32_t x) {
    return __hip_atomic_load(&P[x], __ATOMIC_RELAXED, __HIP_MEMORY_SCOPE_AGENT);
}
__device__ __forceinline__ uint32_t uf_find(uint32_t* P, uint32_t x) {
    uint32_t p = pload(P, x);
    while (p != x) {
        uint32_t gp = pload(P, p);
        if (gp != p)
            __hip_atomic_store(&P[x], gp, __ATOMIC_RELAXED, __HIP_MEMORY_SCOPE_AGENT);
        x = p; p = gp;
    }
    return x;
}
__device__ uint32_t uf_union(uint32_t* P, uint32_t a, uint32_t b) {
    uint32_t ra = uf_find(P, a);
    uint32_t rb = uf_find(P, b);
    while (ra != rb) {
        uint32_t hi = ra > rb ? ra : rb;
        uint32_t lo = ra ^ rb ^ hi;
        uint32_t old = atomicCAS(&P[lo], lo, hi);
        if (old == lo) return 1;  // killed exactly one root
        ra = uf_find(P, old);
        rb = uf_find(P, hi);
    }
    return 0;
}

// pair candidates: j=0..3 owned by tile (E,S,SE,SW), j=4..7 partner roles
__device__ __forceinline__ bool pair_cand(int j, int tile, int txx, int tyy,
                                          int* fam, int* own) {
    switch (j) {
    case 0:  *fam = 0; *own = tile;      return txx < 31;
    case 1:  *fam = 1; *own = tile;      return tyy < 31;
    case 2:  *fam = 2; *own = tile;      return (txx < 31) && (tyy < 31);
    case 3:  *fam = 3; *own = tile;      return (txx > 0) && (tyy < 31);
    case 4:  *fam = 0; *own = tile - 1;  return txx > 0;
    case 5:  *fam = 1; *own = tile - 32; return tyy > 0;
    case 6:  *fam = 2; *own = tile - 33; return (txx > 0) && (tyy > 0);
    default: *fam = 3; *own = tile - 31; return (txx < 31) && (tyy > 0);
    }
}

// execute one cross-tile pair's unions (lanes 0-31 active for E/S; lane 0 for corners)
__device__ uint32_t do_pair(const uint8_t* __restrict__ desc,
                            uint32_t* __restrict__ parent,
                            int fam, int owner, int L) {
    const uint8_t* dT = desc + ((uint32_t)owner << 7);
    uint32_t nT = (uint32_t)owner << 7;
    uint32_t links = 0;
    if (fam == 0) {            // E: owner's right col vs (owner+1)'s left col
        if (L < 32) {
            int tE = owner + 1;
            const uint8_t* dE = desc + ((uint32_t)tE << 7);
            uint32_t nE = (uint32_t)tE << 7;
            uint32_t sR = dT[96 + L];
            if (sR != 0xFFu) {
                uint32_t a = nT + sR;
                uint32_t s0 = dE[64 + L];
                if (s0 != 0xFFu) links += uf_union(parent, a, nE + s0);
                if (L < 31) { uint32_t s1 = dE[64 + L + 1]; if (s1 != 0xFFu) links += uf_union(parent, a, nE + s1); }
                if (L > 0)  { uint32_t s2 = dE[64 + L - 1]; if (s2 != 0xFFu) links += uf_union(parent, a, nE + s2); }
            }
        }
    } else if (fam == 1) {     // S: owner's bottom row vs (owner+32)'s top row
        if (L < 32) {
            int tS = owner + 32;
            const uint8_t* dS = desc + ((uint32_t)tS << 7);
            uint32_t nS = (uint32_t)tS << 7;
            uint32_t sB = dT[32 + L];
            if (sB != 0xFFu) {
                uint32_t a = nT + sB;
                uint32_t s0 = dS[L];
                if (s0 != 0xFFu) links += uf_union(parent, a, nS + s0);
                if (L < 31) { uint32_t s1 = dS[L + 1]; if (s1 != 0xFFu) links += uf_union(parent, a, nS + s1); }
                if (L > 0)  { uint32_t s2 = dS[L - 1]; if (s2 != 0xFFu) links += uf_union(parent, a, nS + s2); }
            }
        }
    } else if (fam == 2) {     // SE corner: owner (31,31) vs (owner+33) (0,0)
        if (L == 0) {
            int tSE = owner + 33;
            uint32_t sB = dT[63];
            uint32_t sQ = desc[((uint32_t)tSE << 7)];
            if (sB != 0xFFu && sQ != 0xFFu)
                links += uf_union(parent, nT + sB, ((uint32_t)tSE << 7) + sQ);
        }
    } else {                   // SW corner: owner (31,0) vs (owner+31) (0,31)
        if (L == 0) {
            int tSW = owner + 31;
            uint32_t sB = dT[32];
            uint32_t sQ = desc[((uint32_t)tSW << 7) + 31];
            if (sB != 0xFFu && sQ != 0xFFu)
                links += uf_union(parent, nT + sB, ((uint32_t)tSW << 7) + sQ);
        }
    }
    return links;
}

// ---------------- kernels ---------------------------------------------------
__global__ void k_open2(const float* __restrict__ img, const float* __restrict__ lab,
                        float* __restrict__ op0, float* __restrict__ op1,
                        uint32_t* cbase) {
    __shared__ uint32_t S[5168];
    int bank = blockIdx.x >> 9;
    do_open_strip(bank ? lab : img, bank ? op1 : op0, cbase + bank * 16,
                  blockIdx.x & 511, S);
}

// tile CCL + fused cross-tile border via pair rendezvous (second arriver works)
__global__ __launch_bounds__(256) void k_cclb(const float* __restrict__ op0,
                                              const float* __restrict__ op1,
                                              uint8_t* __restrict__ d0,
                                              uint8_t* __restrict__ d1,
                                              uint32_t* __restrict__ p0,
                                              uint32_t* __restrict__ p1,
                                              uint32_t* cbase) {
    __shared__ uint32_t S[8320];
    int bank = blockIdx.x >> 10;
    int wave = threadIdx.x >> 6, L = threadIdx.x & 63;
    uint32_t* M = S + wave * 2080;
    float thr = calc_thr(cbase, bank);
    int tile = ((blockIdx.x & 1023) << 2) + wave;
    const uint8_t* desc = bank ? d1 : d0;
    uint32_t* parent    = bank ? p1 : p0;
    uint32_t* F = cbase + CNT_WORDS + bank * (4 * NT);

    do_ccl_tile(bank ? op1 : op0, (uint8_t*)desc, parent, cbase, bank, tile, L,
                M, M + 32, M + 1056, thr);

    // rendezvous: release our desc/parent stores, bump the 8 pair flags
    // (one vector atomic, lanes 0-7), second arriver executes the pair.
    int tt = tile & 1023;
    int tyy = tt >> 5, txx = tt & 31;
    __threadfence();
    uint32_t go = 0;
    if (L < 8) {
        int fam, own;
        if (pair_cand(L, tile, txx, tyy, &fam, &own))
            go = (atomicAdd(&F[fam * NT + own], 1u) == 1u) ? 1u : 0u;
    }
    unsigned long long bal = __ballot(go != 0);
    uint32_t links = 0;
    if (bal) {
        __threadfence();  // acquire: partner's desc/parent stores
        while (bal) {
            int j = __ffsll((long long)bal) - 1; bal &= bal - 1;
            int fam, own;
            pair_cand(j, tile, txx, tyy, &fam, &own);
            links += do_pair(desc, parent, fam, own, L);
        }
    }
    for (int off = 32; off > 0; off >>= 1) links += __shfl_down(links, off);
    if (L == 0 && links) atomicAdd(&cbase[LKW(bank, tile & 7)], links);
}

__global__ void k_final(const uint32_t* __restrict__ c, float* __restrict__ out) {
    unsigned long long fc0 = 0, fc1 = 0;
    uint32_t gl0 = 0, gl1 = 0;
    for (int s = 0; s < 8; s++) {
        fc0 += *(const unsigned long long*)&c[FCW(0, s)];
        fc1 += *(const unsigned long long*)&c[FCW(1, s)];
        gl0 += c[LKW(0, s)];
        gl1 += c[LKW(1, s)];
    }
    uint32_t nf0 = (uint32_t)fc0, lc0 = (uint32_t)(fc0 >> 32);
    uint32_t nf1 = (uint32_t)fc1, lc1 = (uint32_t)(fc1 >> 32);
    uint32_t z0 = c[2], z1 = c[18];
    uint32_t comps0 = lc0 - gl0;   // total fg components (incl. pixel-0 singleton)
    uint32_t comps1 = lc1 - gl1;
    float ccs  = (float)(comps0 - z0 + ((nf0 < (uint32_t)NPIX || z0) ? 1u : 0u));
    float ccsg = (float)(comps1 - z1 + ((nf1 < (uint32_t)NPIX || z1) ? 1u : 0u));
    out[0] = fabsf(ccsg - ccs) / (float)nf1;   // all exact ints < 2^24
}

extern "C" void kernel_launch(void* const* d_in, const int* in_sizes, int n_in,
                              void* d_out, int out_size, void* d_ws, size_t ws_size,
                              hipStream_t stream) {
    const float* img = (const float*)d_in[0];
    const float* lab = (const float*)d_in[1];
    float* out = (float*)d_out;
    char* ws = (char*)d_ws;

    float*    op0 = (float*)ws;                                      // 16 MB
    float*    op1 = (float*)(ws + (size_t)16 * 1024 * 1024);         // 16 MB
    uint8_t*  d0  = (uint8_t*)(ws + (size_t)32 * 1024 * 1024);       // 512 KB
    uint8_t*  d1  = (uint8_t*)(ws + (size_t)32 * 1024 * 1024 + 512 * 1024);
    uint32_t* p0  = (uint32_t*)(ws + (size_t)33 * 1024 * 1024);      // 2 MB
    uint32_t* p1  = (uint32_t*)(ws + (size_t)35 * 1024 * 1024);      // 2 MB
    uint32_t* cnt = (uint32_t*)(ws + (size_t)37 * 1024 * 1024);      // counters + 128 KB flags

    k_zero<<<64, 256, 0, stream>>>(cnt);
    k_open2<<<2 * NB * (HH / RS), 256, 0, stream>>>(img, lab, op0, op1, cnt);
    k_cclb<<<2 * NT / 4, 256, 0, stream>>>(op0, op1, d0, d1, p0, p1, cnt);
    k_final<<<1, 1, 0, stream>>>(cnt, out);
}

// Round 15
// 148.977 us; speedup vs baseline: 2.8968x; 2.8968x over previous
//
#include <hip/hip_runtime.h>
#include <stdint.h>

#define WW 1024
#define HH 1024
#define NB 4
#define HW (HH * WW)
#define NPIX (NB * HW)        // 4194304
#define NT 4096               // 32x32 tiles per input
#define INVALID 0xFFFFFFFFu
#define RS 8                  // rows per open strip

// counter layout (uint32 words):
//   bank b misc at b*16: [0]=min_bits [1]=max_bits [2]=root0 flag
//   fg/comp u64 slots:  word FCW(b,s) = 32  + (b*8+s)*16   (8 slots/input, 64B apart)
//   link u32 slots:     word LKW(b,s) = 288 + (b*8+s)*16
#define FCW(b,s) (32 + ((b)*8+(s))*16)
#define LKW(b,s) (288 + ((b)*8+(s))*16)
#define CNT_WORDS 544

__global__ void k_zero(uint32_t* c) {
    for (int i = threadIdx.x; i < CNT_WORDS; i += 256) c[i] = 0;
    __syncthreads();
    if (threadIdx.x == 0) { c[0] = 0x7F800000u; c[16] = 0x7F800000u; }
}

// ---- open strip: cross erode+dilate + per-input min/max (r11-identical) ----
__device__ __forceinline__ void do_open_strip(const float* __restrict__ in,
                                              float* __restrict__ out,
                                              uint32_t* c, int strip, uint32_t* S) {
    int b  = strip >> 7;
    int y0 = (strip & 127) * RS;
    int t  = threadIdx.x;
    float* sx = (float*)S;
    float* sw = (float*)S + 2580;
    float* smin = (float*)S + 5160;
    float* smax = (float*)S + 5164;
    const float4* inb = (const float4*)(in + (size_t)b * HW);
    float4* outb      = (float4*)(out + (size_t)b * HW);

    float4 A[RS + 4];
    #pragma unroll
    for (int j = 0; j < RS + 4; j++) {
        int iy = y0 - 2 + j;
        if (iy >= 0 && iy < HH) A[j] = inb[iy * 256 + t];
        else A[j] = make_float4(1e10f, 1e10f, 1e10f, 1e10f);  // erosion pad
    }
    #pragma unroll
    for (int rr = 0; rr < RS + 2; rr++) { sx[rr * 258 + t + 1] = A[rr + 1].x; sw[rr * 258 + t + 1] = A[rr + 1].w; }
    if (t < RS + 2) { sw[t * 258 + 0] = 1e10f; sx[t * 258 + 257] = 1e10f; }
    __syncthreads();

    float4 E[RS + 2];
    #pragma unroll
    for (int rr = 0; rr < RS + 2; rr++) {
        int ey = y0 - 1 + rr;
        float lw = sw[rr * 258 + t], rw = sx[rr * 258 + t + 2];
        float4 v = A[rr + 1];
        float hx = fminf(fminf(lw, v.x), v.y);
        float hy = fminf(fminf(v.x, v.y), v.z);
        float hz = fminf(fminf(v.y, v.z), v.w);
        float hw = fminf(fminf(v.z, v.w), rw);
        float4 e;
        e.x = fminf(hx, fminf(A[rr].x, A[rr + 2].x));
        e.y = fminf(hy, fminf(A[rr].y, A[rr + 2].y));
        e.z = fminf(hz, fminf(A[rr].z, A[rr + 2].z));
        e.w = fminf(hw, fminf(A[rr].w, A[rr + 2].w));
        if (ey < 0 || ey >= HH) e = make_float4(-1e10f, -1e10f, -1e10f, -1e10f);
        E[rr] = e;
    }
    __syncthreads();

    #pragma unroll
    for (int d = 0; d < RS; d++) { sx[d * 258 + t + 1] = E[d + 1].x; sw[d * 258 + t + 1] = E[d + 1].w; }
    if (t < RS) { sw[t * 258 + 0] = -1e10f; sx[t * 258 + 257] = -1e10f; }
    __syncthreads();

    float lmin = __uint_as_float(0x7F800000u);
    float lmax = 0.0f;
    #pragma unroll
    for (int d = 0; d < RS; d++) {
        float lw = sw[d * 258 + t], rw = sx[d * 258 + t + 2];
        float4 v = E[d + 1];
        float hx = fmaxf(fmaxf(lw, v.x), v.y);
        float hy = fmaxf(fmaxf(v.x, v.y), v.z);
        float hz = fmaxf(fmaxf(v.y, v.z), v.w);
        float hw = fmaxf(fmaxf(v.z, v.w), rw);
        float4 o;
        o.x = fmaxf(hx, fmaxf(E[d].x, E[d + 2].x));
        o.y = fmaxf(hy, fmaxf(E[d].y, E[d + 2].y));
        o.z = fmaxf(hz, fmaxf(E[d].z, E[d + 2].z));
        o.w = fmaxf(hw, fmaxf(E[d].w, E[d + 2].w));
        outb[(y0 + d) * 256 + t] = o;
        lmin = fminf(lmin, fminf(fminf(o.x, o.y), fminf(o.z, o.w)));
        lmax = fmaxf(lmax, fmaxf(fmaxf(o.x, o.y), fmaxf(o.z, o.w)));
    }
    for (int off = 32; off > 0; off >>= 1) {
        lmin = fminf(lmin, __shfl_down(lmin, off));
        lmax = fmaxf(lmax, __shfl_down(lmax, off));
    }
    if ((t & 63) == 0) { smin[t >> 6] = lmin; smax[t >> 6] = lmax; }
    __syncthreads();
    if (t == 0) {
        float m0 = fminf(fminf(smin[0], smin[1]), fminf(smin[2], smin[3]));
        float m1 = fmaxf(fmaxf(smax[0], smax[1]), fmaxf(smax[2], smax[3]));
        atomicMin(&c[0], __float_as_uint(m0));  // non-negative floats: bit order == float order
        atomicMax(&c[1], __float_as_uint(m1));
    }
}

// exact binarize threshold: smallest float B with (B-mn)/denom >= 0.5;
// v >= B is then bitwise identical to the reference predicate for every v.
__device__ __forceinline__ float calc_thr(const uint32_t* c, int bank) {
    float mn = __uint_as_float(c[bank * 16 + 0]);
    float mx = __uint_as_float(c[bank * 16 + 1]);
    float denom = (mx - mn) + 1e-10f;   // reference association order
    uint32_t lo = 0, hi = 0x7F800000u;
    while (lo < hi) {
        uint32_t mid = (lo + hi) >> 1;
        float q = (__uint_as_float(mid) - mn) / denom;  // IEEE f32 div
        if (q >= 0.5f) hi = mid; else lo = mid + 1;
    }
    return __uint_as_float(lo);
}

// ---------------- LDS union-find (wave-private region) ----------------------
__device__ __forceinline__ uint32_t lload(uint32_t* lp, uint32_t x) {
    return __hip_atomic_load(&lp[x], __ATOMIC_RELAXED, __HIP_MEMORY_SCOPE_WORKGROUP);
}
__device__ __forceinline__ uint32_t lfind(uint32_t* lp, uint32_t x) {
    uint32_t p = lload(lp, x);
    while (p != x) {
        uint32_t gp = lload(lp, p);
        if (gp != p)
            __hip_atomic_store(&lp[x], gp, __ATOMIC_RELAXED, __HIP_MEMORY_SCOPE_WORKGROUP);
        x = p; p = gp;
    }
    return x;
}
__device__ uint32_t lunion(uint32_t* lp, uint32_t a, uint32_t b) {
    uint32_t ra = lfind(lp, a), rb = lfind(lp, b);
    while (ra != rb) {
        uint32_t hi = ra > rb ? ra : rb;
        uint32_t lo = ra ^ rb ^ hi;
        uint32_t old = atomicCAS(&lp[lo], lo, hi);
        if (old == lo) return 1;  // killed exactly one root
        ra = lfind(lp, old);
        rb = lfind(lp, hi);
    }
    return 0;
}
__device__ __forceinline__ int run_len(uint32_t bits) {  // consecutive 1s from bit 0
    return (int)__builtin_ctzll(~(uint64_t)bits);
}

// ---- binarize + tile-local run CCL + compact border-node emit (r9) ---------
__device__ void do_ccl_tile(const float* __restrict__ opened, uint8_t* __restrict__ desc,
                            uint32_t* __restrict__ parent, uint32_t* cbase, int bank,
                            int tile, int L, uint32_t* M, uint32_t* LP, uint32_t* SM,
                            float thr) {
    int b  = tile >> 10;
    int tt = tile & 1023;
    int ty0 = (tt >> 5) << 5;
    int tx0 = (tt & 31) << 5;
    uint32_t base = (uint32_t)b * HW + (uint32_t)ty0 * WW + tx0;

    #pragma unroll
    for (int q = 0; q < 4; q++) {
        uint32_t u = (uint32_t)L + 64u * q;
        ((uint4*)LP)[u] = make_uint4(4*u, 4*u+1, 4*u+2, 4*u+3);
        ((uint4*)SM)[u] = make_uint4(INVALID, INVALID, INVALID, INVALID);
    }

    // dense loads: lane L covers row (L>>3)+8q, cols (L&7)*4..+3
    int r8 = L >> 3, c8 = (L & 7) << 2;
    uint32_t fgcnt = 0;
    #pragma unroll
    for (int q = 0; q < 4; q++) {
        int rr = r8 + 8 * q;
        float4 v = *(const float4*)(opened + base + (uint32_t)rr * WW + c8);
        uint32_t pb = (v.x >= thr ? 1u : 0u) | (v.y >= thr ? 2u : 0u)
                    | (v.z >= thr ? 4u : 0u) | (v.w >= thr ? 8u : 0u);
        fgcnt += __popc(pb);
        uint32_t part = pb << c8;
        part |= __shfl_xor(part, 1, 8);
        part |= __shfl_xor(part, 2, 8);
        part |= __shfl_xor(part, 4, 8);
        if ((L & 7) == 0) M[rr] = part;
    }
    __syncthreads();

    // unions: lane owns half-row (r = L>>1, half h = L&1)
    int r = L >> 1, h = L & 1;
    uint32_t rowm = M[r];
    uint32_t halfsel = 0xFFFFu << (16 * h);
    uint32_t starts = (rowm & ~(rowm << 1)) & halfsel;
    uint32_t runs = __popc(starts);
    uint32_t links = 0;
    if (r > 0 && starts) {
        uint32_t up = M[r - 1];
        uint32_t w0 = starts;
        while (w0) {
            int lx = __builtin_ctz(w0); w0 &= w0 - 1;
            int e = lx + run_len(rowm >> lx) - 1;
            int lo = lx ? lx - 1 : 0;
            int hi = (e >= 31) ? 31 : e + 1;
            uint32_t hm = (hi == 31) ? 0xFFFFFFFFu : ((1u << (hi + 1)) - 1u);
            uint32_t w = up & hm & ~((1u << lo) - 1u);
            uint32_t repA = ((uint32_t)r << 5) + e;
            while (w) {
                int xs = __builtin_ctz(w);
                int xe = xs + run_len(up >> xs) - 1;
                links += lunion(LP, repA, (((uint32_t)r - 1) << 5) + (uint32_t)xe);
                w = (xe >= 31) ? 0u : (w & ~((1u << (xe + 1)) - 1u));
            }
        }
    }
    __syncthreads();

    // pixel-0 / label-0: isolated fg singleton at pixel 0 (all nbrs intra-tile)
    if (tile == 0 && L == 0) {
        if ((rowm & 1u) && !(rowm & 2u) && LP[0] == 0u) atomicOr(&cbase[bank * 16 + 2], 1u);
    }

    // border slot assignment: lane handles positions 2L, 2L+1; lfind from the
    // pixel's RUN REP (run end) — non-rep pixels are never linked in LP.
    uint32_t rk[2]; bool fgk[2];
    #pragma unroll
    for (int j = 0; j < 2; j++) {
        int k = 2 * L + j;
        int li = (k < 32) ? k
               : (k < 64) ? (31 * 32 + (k - 32))
               : (k < 96) ? ((k - 64) << 5)
                          : (((k - 96) << 5) + 31);
        int ly = li >> 5, lx = li & 31;
        uint32_t rm = M[ly];
        bool f = (rm >> lx) & 1u;
        fgk[j] = f;
        if (f) {
            int e = lx + run_len(rm >> lx) - 1;
            rk[j] = lfind(LP, ((uint32_t)ly << 5) + (uint32_t)e);
            atomicMin(&SM[rk[j]], (uint32_t)k);
        }
    }
    __syncthreads();

    uint32_t nodebase = (uint32_t)tile << 7;
    uint32_t d2 = 0;
    #pragma unroll
    for (int j = 0; j < 2; j++) {
        int k = 2 * L + j;
        uint32_t sb = 0xFFu;
        if (fgk[j]) {
            uint32_t s = SM[rk[j]];
            sb = s;
            if (s == (uint32_t)k) parent[nodebase + k] = nodebase + k;  // canonical only
        }
        d2 |= sb << (8 * j);
    }
    ((uint16_t*)desc)[((uint32_t)tile << 6) + L] = (uint16_t)d2;

    uint32_t pk = (fgcnt << 20) | (runs << 10) | links;
    for (int off = 32; off > 0; off >>= 1) pk += __shfl_down(pk, off);
    if (L == 0) {
        uint32_t fgs = pk >> 20, rns = (pk >> 10) & 1023u, lks = pk & 1023u;
        unsigned long long v = ((unsigned long long)(rns - lks) << 32) | fgs;
        if (v) atomicAdd((unsigned long long*)&cbase[FCW(bank, tile & 7)], v);
    }
    __syncthreads();
}

// ---------------- global union-find on compact nodes (device scope) ---------
__device__ __forceinline__ uint32_t pload(uint32_t* P, uint32_t x) {
    return __hip_atomic_load(&P[x], __ATOMIC_RELAXED, __HIP_MEMORY_SCOPE_AGENT);
}
__device__ __forceinline__ uint32_t uf_find(uint32_t* P, uint32_t x) {
    uint32_t p = pload(P, x);
    while (p != x) {
        uint32_t gp = pload(P, p);
        if (gp != p)
            __hip_atomic_store(&P[x], gp, __ATOMIC_RELAXED, __HIP_MEMORY_SCOPE_AGENT);
        x = p; p = gp;
    }
    return x;
}
__device__ uint32_t uf_union(uint32_t* P, uint32_t a, uint32_t b) {
    uint32_t ra = uf_find(P, a);
    uint32_t rb = uf_find(P, b);
    while (ra != rb) {
        uint32_t hi = ra > rb ? ra : rb;
        uint32_t lo = ra ^ rb ^ hi;
        uint32_t old = atomicCAS(&P[lo], lo, hi);
        if (old == lo) return 1;  // killed exactly one root
        ra = uf_find(P, old);
        rb = uf_find(P, hi);
    }
    return 0;
}

// cross-tile edges via descriptors; one wave per tile (r9-identical)
__device__ void do_border_tile(const uint8_t* __restrict__ desc,
                               uint32_t* __restrict__ parent,
                               uint32_t* cbase, int inb, int tile, int L) {
    int tt = tile & 1023;
    int tyy = tt >> 5, txx = tt & 31;
    const uint8_t* dT = desc + ((uint32_t)tile << 7);
    uint32_t nT = (uint32_t)tile << 7;
    uint32_t links = 0;

    if (L < 32) {
        if (txx < 31) {
            int tE = tile + 1;
            const uint8_t* dE = desc + ((uint32_t)tE << 7);
            uint32_t nE = (uint32_t)tE << 7;
            uint32_t sR = dT[96 + L];
            if (sR != 0xFFu) {
                uint32_t a = nT + sR;
                uint32_t s0 = dE[64 + L];
                if (s0 != 0xFFu) links += uf_union(parent, a, nE + s0);
                if (L < 31) { uint32_t s1 = dE[64 + L + 1]; if (s1 != 0xFFu) links += uf_union(parent, a, nE + s1); }
                if (L > 0)  { uint32_t s2 = dE[64 + L - 1]; if (s2 != 0xFFu) links += uf_union(parent, a, nE + s2); }
            }
        }
    } else {
        int x = L - 32;
        if (tyy < 31) {
            int tS = tile + 32;
            const uint8_t* dS = desc + ((uint32_t)tS << 7);
            uint32_t nS = (uint32_t)tS << 7;
            uint32_t sB = dT[32 + x];
            if (sB != 0xFFu) {
                uint32_t a = nT + sB;
                uint32_t s0 = dS[x];
                if (s0 != 0xFFu) links += uf_union(parent, a, nS + s0);
                if (x < 31) { uint32_t s1 = dS[x + 1]; if (s1 != 0xFFu) links += uf_union(parent, a, nS + s1); }
                if (x > 0)  { uint32_t s2 = dS[x - 1]; if (s2 != 0xFFu) links += uf_union(parent, a, nS + s2); }
            }
        }
    }
    if (L == 0 && tyy < 31 && txx < 31) {        // SE corner
        int tSE = tile + 33;
        uint32_t sB = dT[63];
        uint32_t sQ = desc[((uint32_t)tSE << 7)];
        if (sB != 0xFFu && sQ != 0xFFu) links += uf_union(parent, nT + sB, ((uint32_t)tSE << 7) + sQ);
    }
    if (L == 1 && tyy < 31 && txx > 0) {         // SW corner
        int tSW = tile + 31;
        uint32_t sB = dT[32];
        uint32_t sQ = desc[((uint32_t)tSW << 7) + 31];
        if (sB != 0xFFu && sQ != 0xFFu) links += uf_union(parent, nT + sB, ((uint32_t)tSW << 7) + sQ);
    }

    for (int off = 32; off > 0; off >>= 1) links += __shfl_down(links, off);
    if (L == 0 && links) atomicAdd(&cbase[LKW(inb, tile & 7)], links);
}

// ---------------- kernels: both inputs per dispatch -------------------------
__global__ void k_open2(const float* __restrict__ img, const float* __restrict__ lab,
                        float* __restrict__ op0, float* __restrict__ op1,
                        uint32_t* cbase) {
    __shared__ uint32_t S[5168];
    int bank = blockIdx.x >> 9;
    do_open_strip(bank ? lab : img, bank ? op1 : op0, cbase + bank * 16,
                  blockIdx.x & 511, S);
}

__global__ __launch_bounds__(256) void k_ccl2(const float* __restrict__ op0,
                                              const float* __restrict__ op1,
                                              uint8_t* __restrict__ d0,
                                              uint8_t* __restrict__ d1,
                                              uint32_t* __restrict__ p0,
                                              uint32_t* __restrict__ p1,
                                              uint32_t* cbase) {
    __shared__ uint32_t S[8320];
    int bank = blockIdx.x >> 10;
    int wave = threadIdx.x >> 6, L = threadIdx.x & 63;
    uint32_t* M = S + wave * 2080;
    float thr = calc_thr(cbase, bank);
    int tile = ((blockIdx.x & 1023) << 2) + wave;
    do_ccl_tile(bank ? op1 : op0, bank ? d1 : d0, bank ? p1 : p0, cbase, bank,
                tile, L, M, M + 32, M + 1056, thr);
}

__global__ __launch_bounds__(256) void k_border(const uint8_t* __restrict__ desc0,
                                                const uint8_t* __restrict__ desc1,
                                                uint32_t* __restrict__ parent0,
                                                uint32_t* __restrict__ parent1,
                                                uint32_t* cbase) {
    int inb  = blockIdx.x >> 10;
    int wave = threadIdx.x >> 6, L = threadIdx.x & 63;
    int tile = ((blockIdx.x & 1023) << 2) + wave;
    do_border_tile(inb ? desc1 : desc0, inb ? parent1 : parent0, cbase, inb, tile, L);
}

__global__ void k_final(const uint32_t* __restrict__ c, float* __restrict__ out) {
    unsigned long long fc0 = 0, fc1 = 0;
    uint32_t gl0 = 0, gl1 = 0;
    for (int s = 0; s < 8; s++) {
        fc0 += *(const unsigned long long*)&c[FCW(0, s)];
        fc1 += *(const unsigned long long*)&c[FCW(1, s)];
        gl0 += c[LKW(0, s)];
        gl1 += c[LKW(1, s)];
    }
    uint32_t nf0 = (uint32_t)fc0, lc0 = (uint32_t)(fc0 >> 32);
    uint32_t nf1 = (uint32_t)fc1, lc1 = (uint32_t)(fc1 >> 32);
    uint32_t z0 = c[2], z1 = c[18];
    uint32_t comps0 = lc0 - gl0;   // total fg components (incl. pixel-0 singleton)
    uint32_t comps1 = lc1 - gl1;
    float ccs  = (float)(comps0 - z0 + ((nf0 < (uint32_t)NPIX || z0) ? 1u : 0u));
    float ccsg = (float)(comps1 - z1 + ((nf1 < (uint32_t)NPIX || z1) ? 1u : 0u));
    out[0] = fabsf(ccsg - ccs) / (float)nf1;   // all exact ints < 2^24
}

extern "C" void kernel_launch(void* const* d_in, const int* in_sizes, int n_in,
                              void* d_out, int out_size, void* d_ws, size_t ws_size,
                              hipStream_t stream) {
    const float* img = (const float*)d_in[0];
    const float* lab = (const float*)d_in[1];
    float* out = (float*)d_out;
    char* ws = (char*)d_ws;

    float*    op0 = (float*)ws;                                      // 16 MB
    float*    op1 = (float*)(ws + (size_t)16 * 1024 * 1024);         // 16 MB
    uint8_t*  d0  = (uint8_t*)(ws + (size_t)32 * 1024 * 1024);       // 512 KB
    uint8_t*  d1  = (uint8_t*)(ws + (size_t)32 * 1024 * 1024 + 512 * 1024);
    uint32_t* p0  = (uint32_t*)(ws + (size_t)33 * 1024 * 1024);      // 2 MB
    uint32_t* p1  = (uint32_t*)(ws + (size_t)35 * 1024 * 1024);      // 2 MB
    uint32_t* cnt = (uint32_t*)(ws + (size_t)37 * 1024 * 1024);      // 2176 B

    k_zero<<<1, 256, 0, stream>>>(cnt);
    k_open2<<<2 * NB * (HH / RS), 256, 0, stream>>>(img, lab, op0, op1, cnt);
    k_ccl2<<<2 * NT / 4, 256, 0, stream>>>(op0, op1, d0, d1, p0, p1, cnt);
    k_border<<<2 * NT / 4, 256, 0, stream>>>(d0, d1, p0, p1, cnt);
    k_final<<<1, 1, 0, stream>>>(cnt, out);
}